// Round 5
// baseline (52.368 us; speedup 1.0000x reference)
//
#include <hip/hip_runtime.h>

#define Nn 8
#define Cc 4
#define Hh 256
#define Ww 256

// Workspace layout (bytes):
//   g       : [n][k][j] ushort4 (per-class row distance, <=512) -> 4,194,304
//   partials: [2048] float                                      ->     8,192
//   counter : 1 uint (ticket for last-block reduction)
#define OFF_G    0
#define OFF_PART 4194304
#define OFF_CNT  4202496

// ---------------------------------------------------------------------------
// Kernel A: exact per-row 1-D nearest-class distance via 256-bit class masks.
// (unchanged from R3 — this round's A/B isolates kernel B)
// ---------------------------------------------------------------------------
__global__ __launch_bounds__(1024) void edt_rows_kernel(
    const int* __restrict__ tgt, ushort4* __restrict__ g,
    unsigned* __restrict__ counter) {
  // [row][class][guard0, w0..w3, guard5, pad] ; stride 7 -> <=2-way (free)
  __shared__ unsigned long long smp[8][4][7];
  const int tid = threadIdx.x;
  const int lane = tid & 63;
  const int n = blockIdx.x >> 5;          // 32 blocks per sample
  const int k0 = (blockIdx.x & 31) * 8;

  if (blockIdx.x == 0 && tid == 0) *counter = 0u;  // visible to next kernel
  if (tid < 64) {  // zero the guard words (idx 0 and 5)
    smp[tid >> 3][(tid >> 1) & 3][(tid & 1) * 5] = 0ull;
  }
  {
    const int r = tid >> 7;               // row 0..7
    const int h = (tid >> 6) & 1;         // 64-bit word half
    const int j1 = h * 64 + lane;
    const int rowOff = (n * Hh + k0 + r) * Ww;
    const int t1 = tgt[rowOff + j1];
    const int t2 = tgt[rowOff + j1 + 128];
#pragma unroll
    for (int c = 0; c < Cc; ++c) {
      const unsigned long long m1 = __ballot(t1 == c);
      const unsigned long long m2 = __ballot(t2 == c);
      if (lane == 0) {
        smp[r][c][1 + h] = m1;
        smp[r][c][3 + h] = m2;
      }
    }
  }
  __syncthreads();

  const int r = tid >> 7;                 // row 0..7
  const int jj = tid & 127;
  const int rowOut = (n * Hh + k0 + r) * Ww;
#pragma unroll
  for (int half = 0; half < 2; ++half) {
    const int j = jj + half * 128;
    const int S = j + 32;                 // padded bitspace: orig bit x = 64+x
    const int word = S >> 6;              // 0..4
    const int sh = S & 63;
    int d[4];
#pragma unroll
    for (int c = 0; c < Cc; ++c) {
      const unsigned long long* M = smp[r][c];
      const unsigned long long lo = M[word];
      const unsigned long long hi = M[word + 1];
      const unsigned long long win =
          sh ? ((lo >> sh) | (hi << (64 - sh))) : lo;  // bits [j-32, j+31]
      const unsigned long long ml = win & 0x1FFFFFFFFull;  // <= pixel (bit 32)
      const unsigned long long mr = win >> 32;             // >= pixel
      int dd;
      if (ml | mr) {
        const int dl = ml ? (__builtin_clzll(ml) - 31) : 512;
        const int dr = mr ? (int)__builtin_ctzll(mr) : 512;
        dd = min(dl, dr);
      } else {
        // exact rare fallback: full 4-word scan both directions
        int dl = 512, dr = 512;
#pragma unroll
        for (int w = 3; w >= 0; --w) {
          if (w * 64 <= j) {
            unsigned long long m = M[1 + w];
            if (w == (j >> 6)) {
              const int r6 = j & 63;
              m &= (r6 == 63) ? ~0ull : ((1ull << (r6 + 1)) - 1ull);
            }
            if (m && dl == 512) dl = j - (w * 64 + 63 - __builtin_clzll(m));
          }
        }
#pragma unroll
        for (int w = 0; w < 4; ++w) {
          if (w * 64 + 63 >= j) {
            unsigned long long m = M[1 + w];
            if (w == (j >> 6)) m &= ~((1ull << (j & 63)) - 1ull);
            if (m && dr == 512) dr = w * 64 + (int)__builtin_ctzll(m) - j;
          }
        }
        dd = min(min(dl, dr), 512);
      }
      d[c] = dd;
    }
    ushort4 out;
    out.x = (unsigned short)d[0];
    out.y = (unsigned short)d[1];
    out.z = (unsigned short)d[2];
    out.w = (unsigned short)d[3];
    g[rowOut + j] = out;                  // coalesced: lanes = consecutive j
  }
}

// ---------------------------------------------------------------------------
// Kernel B (fused, one pixel per thread): tile 4i x 64j, 2048 blocks x 256thr
// = 8 waves/SIMD. 17 independent g-loads, integer mad/min window (exact
// >81 full-column fallback), in-register softmax from natural-layout logits,
// loss, block reduction, ticketed last-block final reduction.
// ---------------------------------------------------------------------------
__global__ __launch_bounds__(256) void fused_kernel(
    const float* __restrict__ in, const ushort4* __restrict__ g,
    float* __restrict__ partials, unsigned* __restrict__ counter,
    float* __restrict__ out) {
  __shared__ float s_w[4];
  __shared__ int s_flag;
  __shared__ float s_red[256];
  const int bid = blockIdx.x;   // 8 n * 64 i-tiles * 4 j-tiles = 2048
  const int n = bid >> 8;
  const int it = (bid >> 2) & 63;
  const int jt = bid & 3;
  const int tid = threadIdx.x;
  const int j = jt * 64 + (tid & 63);
  const int i = it * 4 + (tid >> 6);

  const ushort4* gp = g + n * (Hh * Ww) + j;  // + k*Ww

  int d0 = 0x7fffffff, d1 = 0x7fffffff, d2 = 0x7fffffff, d3 = 0x7fffffff;
#pragma unroll
  for (int kq = 0; kq < 17; ++kq) {
    int k = i - 8 + kq;
    k = (k < 0) ? 0 : ((k > Hh - 1) ? (Hh - 1) : k);  // dup candidates: safe
    const ushort4 gv = gp[k * Ww];        // independent, coalesced, L2-hot
    const int di = i - k;
    const int dd = di * di;
    d0 = min(d0, (int)gv.x * (int)gv.x + dd);   // u24 mad + int min
    d1 = min(d1, (int)gv.y * (int)gv.y + dd);
    d2 = min(d2, (int)gv.z * (int)gv.z + dd);
    d3 = min(d3, (int)gv.w * (int)gv.w + dd);
  }
  // Exactness: excluded k have (i-k)^2 >= 81; if min <= 81 window is exact.
  if (__any(max(max(d0, d1), max(d2, d3)) > 81)) {  // rare exact fallback
    for (int k = 0; k < Hh; ++k) {
      const ushort4 gv = gp[k * Ww];
      const int di = i - k;
      const int dd = di * di;
      d0 = min(d0, (int)gv.x * (int)gv.x + dd);
      d1 = min(d1, (int)gv.y * (int)gv.y + dd);
      d2 = min(d2, (int)gv.z * (int)gv.z + dd);
      d3 = min(d3, (int)gv.w * (int)gv.w + dd);
    }
  }

  // exact conversions: all d2 < 2^24
  const float f0 = (float)d0, f1 = (float)d1;
  const float f2 = (float)d2, f3 = (float)d3;

  const long cs = (long)Hh * Ww;          // class stride in floats
  const float* lp = in + ((long)(n * Cc) * Hh + i) * Ww + j;
  const float x0 = lp[0];
  const float x1 = lp[cs];
  const float x2 = lp[2 * cs];
  const float x3 = lp[3 * cs];
  const float mx = fmaxf(fmaxf(x0, x1), fmaxf(x2, x3));
  const float e0 = expf(x0 - mx), e1 = expf(x1 - mx);
  const float e2 = expf(x2 - mx), e3 = expf(x3 - mx);
  const float rs = 1.0f / (e0 + e1 + e2 + e3);
  const float p0 = e0 * rs, p1 = e1 * rs, p2 = e2 * rs, p3 = e3 * rs;
  // own-class d2 is exactly 0 (k=i, g=0); exclude it for dbar
  const int q0 = (d0 == 0) ? 0x7fffffff : d0;
  const int q1 = (d1 == 0) ? 0x7fffffff : d1;
  const int q2 = (d2 == 0) ? 0x7fffffff : d2;
  const int q3 = (d3 == 0) ? 0x7fffffff : d3;
  const float dbar = (float)min(min(q0, q1), min(q2, q3));
  const float pt = (d0 == 0) ? p0 : (d1 == 0) ? p1 : (d2 == 0) ? p2 : p3;
  float contrib = pt * sqrtf(dbar) -
                  (p0 * sqrtf(f0) + p1 * sqrtf(f1) +
                   p2 * sqrtf(f2) + p3 * sqrtf(f3));

  // block reduction (deterministic fixed order)
#pragma unroll
  for (int off = 32; off > 0; off >>= 1) contrib += __shfl_down(contrib, off);
  if ((tid & 63) == 0) s_w[tid >> 6] = contrib;
  __syncthreads();
  if (tid == 0) {
    const float v = (s_w[0] + s_w[1]) + (s_w[2] + s_w[3]);
    partials[bid] = v;
    __threadfence();                      // device-scope: publish partial
    const unsigned t = atomicAdd(counter, 1u);
    s_flag = (t == (unsigned)(gridDim.x - 1));
  }
  __syncthreads();
  if (s_flag) {                           // last block: final reduction
    // 8 independent coherent (atomic) reads -> pipelined, then fixed-order sum
    float v[8];
#pragma unroll
    for (int q = 0; q < 8; ++q)
      v[q] = atomicAdd(&partials[tid + q * 256], 0.0f);
    float a = 0.0f;
#pragma unroll
    for (int q = 0; q < 8; ++q) a += v[q];
    s_red[tid] = a;
    __syncthreads();
    for (int st = 128; st > 0; st >>= 1) {
      if (tid < st) s_red[tid] += s_red[tid + st];
      __syncthreads();
    }
    if (tid == 0)
      out[0] = s_red[0] / (float)(Cc * Nn) / (65536.0f + 1e-6f);
  }
}

extern "C" void kernel_launch(void* const* d_in, const int* in_sizes, int n_in,
                              void* d_out, int out_size, void* d_ws, size_t ws_size,
                              hipStream_t stream) {
  const float* input = (const float*)d_in[0];   // [8,4,256,256] fp32 logits
  const int* target = (const int*)d_in[1];      // [8,256,256] int32
  float* out = (float*)d_out;                   // scalar fp32
  char* ws = (char*)d_ws;
  ushort4* g = (ushort4*)(ws + OFF_G);
  float* partials = (float*)(ws + OFF_PART);
  unsigned* counter = (unsigned*)(ws + OFF_CNT);

  edt_rows_kernel<<<dim3((Nn * Hh) / 8), dim3(1024), 0, stream>>>(target, g,
                                                                  counter);
  fused_kernel<<<dim3(2048), dim3(256), 0, stream>>>(input, g, partials,
                                                     counter, out);
}